// Round 1
// baseline (2132.306 us; speedup 1.0000x reference)
//
#include <hip/hip_runtime.h>

static constexpr int NB   = 384;
static constexpr int SEQL = 256;
static constexpr int NROWS = NB * SEQL; // 98304

// ---------------------------------------------------------------------------
// Featurize + GRU layer-0 input projection:  X[(t*NB+b)*192 + j]
// ---------------------------------------------------------------------------
__global__ __launch_bounds__(192) void featproj_kernel(
    const float* __restrict__ x, const float* __restrict__ emb,
    const float* __restrict__ wih0, const float* __restrict__ bih0,
    float* __restrict__ X)
{
    __shared__ float F[32][33];
    const int tid = threadIdx.x;
    const int m0  = blockIdx.x * 32;

    if (tid < 96) {
        const int r   = tid & 31;
        const int grp = tid >> 5;          // 0,1,2 -> feature groups of 10
        const int m   = m0 + r;            // m = t*NB + b
        const int b   = m % NB;
        const int l   = m / NB;
        const float* xb = x + (size_t)b * (3 * SEQL);
        const float x0 = xb[l], x1 = xb[SEQL + l], x2 = xb[2 * SEQL + l];
        const bool is_angle = (b % 3) == 2;
        float o[10];
        if (is_angle) {
            if (grp < 2) {
                const float a = (grp == 0) ? x0 : x1;
                #pragma unroll
                for (int c = 0; c < 10; ++c) { float d = (float)(c + 1) - a; o[c] = __expf(-d * d); }
            } else {
                float t0 = 1.f, t1 = x2;
                o[0] = 1.f; o[1] = x2;
                #pragma unroll
                for (int c = 2; c < 10; ++c) { float t = 2.f * x2 * t1 - t0; o[c] = t; t0 = t1; t1 = t; }
            }
        } else {
            if (grp < 2) {
                const float xv = (grp == 0) ? x0 : x1;
                int idx = (int)xv; idx = idx < 0 ? 0 : (idx > 118 ? 118 : idx);
                #pragma unroll
                for (int c = 0; c < 10; ++c) o[c] = emb[idx * 10 + c];
            } else {
                #pragma unroll
                for (int c = 0; c < 10; ++c) { float d = (float)(c + 1) - x2; o[c] = __expf(-d * d); }
            }
        }
        #pragma unroll
        for (int c = 0; c < 10; ++c) F[r][grp * 10 + c] = o[c];
    }
    __syncthreads();

    float w[30];
    #pragma unroll
    for (int k = 0; k < 30; ++k) w[k] = wih0[tid * 30 + k];
    const float bj = bih0[tid];
    for (int r = 0; r < 32; ++r) {
        float acc = bj;
        #pragma unroll
        for (int k = 0; k < 30; ++k) acc += F[r][k] * w[k];
        X[(size_t)(m0 + r) * 192 + tid] = acc;
    }
}

// ---------------------------------------------------------------------------
// GRU recurrence. X holds precomputed xt@Wih.T + bih, row = t*NB + b.
// One block per batch row; thread j owns gate-row j (whh row in registers).
// out_batch_major: 0 -> Y row = t*NB+b ; 1 -> Y row = b*SEQL+t
// ---------------------------------------------------------------------------
__global__ __launch_bounds__(192) void gru_kernel(
    const float* __restrict__ X, const float* __restrict__ whh,
    const float* __restrict__ bhh, float* __restrict__ Y, int out_batch_major)
{
    const int b = blockIdx.x;
    const int j = threadIdx.x;
    __shared__ float h[64];
    __shared__ float gis[192], ghs[192];

    float w[64];
    #pragma unroll
    for (int k = 0; k < 64; ++k) w[k] = whh[j * 64 + k];
    const float bj = bhh[j];
    if (j < 64) h[j] = 0.f;
    __syncthreads();

    for (int t = 0; t < SEQL; ++t) {
        const float gi = X[((size_t)t * NB + b) * 192 + j];
        float gh = bj;
        #pragma unroll
        for (int k = 0; k < 64; ++k) gh += h[k] * w[k];
        gis[j] = gi; ghs[j] = gh;
        __syncthreads();
        if (j < 64) {
            const float r = 1.f / (1.f + __expf(-(gis[j] + ghs[j])));
            const float z = 1.f / (1.f + __expf(-(gis[64 + j] + ghs[64 + j])));
            const float n = tanhf(gis[128 + j] + r * ghs[128 + j]);
            const float hn = (1.f - z) * n + z * h[j];
            h[j] = hn;
            const size_t row = out_batch_major ? ((size_t)b * SEQL + t)
                                               : ((size_t)t * NB + b);
            Y[row * 64 + j] = hn;
        }
        __syncthreads();
    }
}

// ---------------------------------------------------------------------------
// Generic GEMM, K=64 fixed: C[m][n] = bias[n] + sum_k A[m][k]*W[n][k]
// BM=128, BN=64. 256 threads, 8x4 micro-tile.
// ---------------------------------------------------------------------------
__global__ __launch_bounds__(256) void gemm64_kernel(
    const float* __restrict__ A, const float* __restrict__ W,
    const float* __restrict__ bias, float* __restrict__ C, int Ncols)
{
    __shared__ float As[128][68];
    __shared__ float WsT[64][68];
    const int tid = threadIdx.x;
    const int m0 = blockIdx.x * 128;
    const int n0 = blockIdx.y * 64;

    #pragma unroll
    for (int p = 0; p < 8; ++p) {
        const int i = tid + p * 256;
        const int r = i >> 4, c4 = i & 15;
        float4 v = *(const float4*)&A[((size_t)(m0 + r)) * 64 + c4 * 4];
        *(float4*)&As[r][c4 * 4] = v;
    }
    #pragma unroll
    for (int p = 0; p < 4; ++p) {
        const int i = tid + p * 256;
        const int n = i >> 4, c4 = i & 15;
        float4 v = *(const float4*)&W[((size_t)(n0 + n)) * 64 + c4 * 4];
        WsT[c4 * 4 + 0][n] = v.x; WsT[c4 * 4 + 1][n] = v.y;
        WsT[c4 * 4 + 2][n] = v.z; WsT[c4 * 4 + 3][n] = v.w;
    }
    __syncthreads();

    const int tx = tid & 15, ty = tid >> 4;
    float acc[8][4] = {};
    #pragma unroll
    for (int k4 = 0; k4 < 16; ++k4) {
        float4 w0 = *(const float4*)&WsT[k4 * 4 + 0][tx * 4];
        float4 w1 = *(const float4*)&WsT[k4 * 4 + 1][tx * 4];
        float4 w2 = *(const float4*)&WsT[k4 * 4 + 2][tx * 4];
        float4 w3 = *(const float4*)&WsT[k4 * 4 + 3][tx * 4];
        #pragma unroll
        for (int i = 0; i < 8; ++i) {
            float4 a = *(const float4*)&As[ty * 8 + i][k4 * 4];
            acc[i][0] += a.x * w0.x + a.y * w1.x + a.z * w2.x + a.w * w3.x;
            acc[i][1] += a.x * w0.y + a.y * w1.y + a.z * w2.y + a.w * w3.y;
            acc[i][2] += a.x * w0.z + a.y * w1.z + a.z * w2.z + a.w * w3.z;
            acc[i][3] += a.x * w0.w + a.y * w1.w + a.z * w2.w + a.w * w3.w;
        }
    }
    const float b0 = bias[n0 + tx * 4 + 0], b1 = bias[n0 + tx * 4 + 1];
    const float b2 = bias[n0 + tx * 4 + 2], b3 = bias[n0 + tx * 4 + 3];
    #pragma unroll
    for (int i = 0; i < 8; ++i) {
        float4 o;
        o.x = acc[i][0] + b0; o.y = acc[i][1] + b1;
        o.z = acc[i][2] + b2; o.w = acc[i][3] + b3;
        *(float4*)&C[((size_t)(m0 + ty * 8 + i)) * Ncols + n0 + tx * 4] = o;
    }
}

// ---------------------------------------------------------------------------
// Attention per (head, batch): online softmax, thread = query row.
// QKV row = b*SEQL + l, 192 wide: q[0:64], k[64:128], v[128:192].
// ---------------------------------------------------------------------------
__global__ __launch_bounds__(256) void attn_kernel(
    const float* __restrict__ QKV, float* __restrict__ O)
{
    const int hh = blockIdx.x;   // head
    const int b  = blockIdx.y;   // batch
    const int q  = threadIdx.x;  // query row
    const float scale = 0.17677669529663687f; // 1/sqrt(32)

    __shared__ float Ks[64][36];
    __shared__ float Vs[64][36];

    float qr[32];
    {
        const float* qrow = QKV + ((size_t)b * SEQL + q) * 192 + hh * 32;
        #pragma unroll
        for (int d4 = 0; d4 < 8; ++d4) {
            float4 v = *(const float4*)(qrow + d4 * 4);
            qr[d4 * 4 + 0] = v.x; qr[d4 * 4 + 1] = v.y;
            qr[d4 * 4 + 2] = v.z; qr[d4 * 4 + 3] = v.w;
        }
    }
    float m = -1e30f, l = 0.f;
    float o[32];
    #pragma unroll
    for (int d = 0; d < 32; ++d) o[d] = 0.f;

    for (int kc = 0; kc < 4; ++kc) {
        #pragma unroll
        for (int p = 0; p < 2; ++p) {
            const int i = threadIdx.x + p * 256;
            const int r = i >> 3, c4 = i & 7;
            const float* src = QKV + ((size_t)b * SEQL + kc * 64 + r) * 192 + 64 + hh * 32 + c4 * 4;
            *(float4*)&Ks[r][c4 * 4] = *(const float4*)src;
            *(float4*)&Vs[r][c4 * 4] = *(const float4*)(src + 64);
        }
        __syncthreads();
        for (int kk = 0; kk < 64; ++kk) {
            float s = 0.f;
            #pragma unroll
            for (int d = 0; d < 32; d += 4) {
                float4 kv = *(const float4*)&Ks[kk][d];
                s += qr[d] * kv.x + qr[d + 1] * kv.y + qr[d + 2] * kv.z + qr[d + 3] * kv.w;
            }
            s *= scale;
            const float mnew = fmaxf(m, s);
            const float corr = __expf(m - mnew);
            const float p    = __expf(s - mnew);
            l = l * corr + p;
            #pragma unroll
            for (int d = 0; d < 32; d += 4) {
                float4 vv = *(const float4*)&Vs[kk][d];
                o[d + 0] = o[d + 0] * corr + p * vv.x;
                o[d + 1] = o[d + 1] * corr + p * vv.y;
                o[d + 2] = o[d + 2] * corr + p * vv.z;
                o[d + 3] = o[d + 3] * corr + p * vv.w;
            }
            m = mnew;
        }
        __syncthreads();
    }
    const float inv = 1.f / l;
    float* orow = O + ((size_t)b * SEQL + q) * 64 + hh * 32;
    #pragma unroll
    for (int d4 = 0; d4 < 8; ++d4) {
        float4 v;
        v.x = o[d4 * 4 + 0] * inv; v.y = o[d4 * 4 + 1] * inv;
        v.z = o[d4 * 4 + 2] * inv; v.w = o[d4 * 4 + 3] * inv;
        *(float4*)(orow + d4 * 4) = v;
    }
}

// ---------------------------------------------------------------------------
// out = LN(A + B) * s + bb   (row-wise over 64), one wave per row
// ---------------------------------------------------------------------------
__global__ __launch_bounds__(256) void add_ln_kernel(
    const float* __restrict__ A, const float* __restrict__ B,
    const float* __restrict__ s, const float* __restrict__ bb,
    float* __restrict__ O)
{
    const size_t row = (size_t)blockIdx.x * 4 + (threadIdx.x >> 6);
    const int lane = threadIdx.x & 63;
    float v = A[row * 64 + lane] + B[row * 64 + lane];
    float sum = v;
    #pragma unroll
    for (int off = 32; off; off >>= 1) sum += __shfl_xor(sum, off);
    const float mean = sum * (1.f / 64.f);
    const float d = v - mean;
    float sq = d * d;
    #pragma unroll
    for (int off = 32; off; off >>= 1) sq += __shfl_xor(sq, off);
    const float var = sq * (1.f / 64.f);
    O[row * 64 + lane] = d * rsqrtf(var + 1e-5f) * s[lane] + bb[lane];
}

// ---------------------------------------------------------------------------
// Fused FFN: Out = relu(relu(X@W1.T + b1) @ W2.T + b2), chunked over 1024.
// 64 rows per block, 256 threads, 4x4 micro-tiles.
// ---------------------------------------------------------------------------
__global__ __launch_bounds__(256) void ffn_kernel(
    const float* __restrict__ Xin, const float* __restrict__ W1,
    const float* __restrict__ b1,  const float* __restrict__ W2,
    const float* __restrict__ b2,  float* __restrict__ Out)
{
    __shared__ float XsT[64][68];  // [k][r]
    __shared__ float Ws [64][68];  // W1c^T then W2c^T, [k|n][n|j]
    __shared__ float HsT[64][68];  // [n][r]

    const int tid = threadIdx.x;
    const int r0  = blockIdx.x * 64;
    const int tx = tid & 15, ty = tid >> 4;

    #pragma unroll
    for (int p = 0; p < 4; ++p) {
        const int i = tid + p * 256;
        const int r = i >> 4, c4 = i & 15;
        float4 v = *(const float4*)&Xin[((size_t)(r0 + r)) * 64 + c4 * 4];
        XsT[c4 * 4 + 0][r] = v.x; XsT[c4 * 4 + 1][r] = v.y;
        XsT[c4 * 4 + 2][r] = v.z; XsT[c4 * 4 + 3][r] = v.w;
    }

    float acc[4][4] = {};
    for (int nc = 0; nc < 16; ++nc) {
        __syncthreads(); // prev accumulate done; Ws/HsT reusable (also covers XsT on nc=0)
        #pragma unroll
        for (int p = 0; p < 4; ++p) {
            const int i = tid + p * 256;
            const int n = i >> 4, c4 = i & 15;
            float4 v = *(const float4*)&W1[((size_t)(nc * 64 + n)) * 64 + c4 * 4];
            Ws[c4 * 4 + 0][n] = v.x; Ws[c4 * 4 + 1][n] = v.y;
            Ws[c4 * 4 + 2][n] = v.z; Ws[c4 * 4 + 3][n] = v.w;
        }
        __syncthreads();

        float hc[4][4] = {};
        #pragma unroll
        for (int k = 0; k < 64; ++k) {
            float4 a = *(const float4*)&XsT[k][ty * 4];
            float4 w = *(const float4*)&Ws[k][tx * 4];
            hc[0][0] += a.x * w.x; hc[0][1] += a.x * w.y; hc[0][2] += a.x * w.z; hc[0][3] += a.x * w.w;
            hc[1][0] += a.y * w.x; hc[1][1] += a.y * w.y; hc[1][2] += a.y * w.z; hc[1][3] += a.y * w.w;
            hc[2][0] += a.z * w.x; hc[2][1] += a.z * w.y; hc[2][2] += a.z * w.z; hc[2][3] += a.z * w.w;
            hc[3][0] += a.w * w.x; hc[3][1] += a.w * w.y; hc[3][2] += a.w * w.z; hc[3][3] += a.w * w.w;
        }
        #pragma unroll
        for (int j = 0; j < 4; ++j) {
            const float bj = b1[nc * 64 + tx * 4 + j];
            #pragma unroll
            for (int i = 0; i < 4; ++i)
                HsT[tx * 4 + j][ty * 4 + i] = fmaxf(hc[i][j] + bj, 0.f);
        }
        __syncthreads(); // W1 reads done, HsT complete
        #pragma unroll
        for (int p = 0; p < 4; ++p) {
            const int i = tid + p * 256;
            const int j = i >> 4, c4 = i & 15;
            float4 v = *(const float4*)&W2[((size_t)j) * 1024 + nc * 64 + c4 * 4];
            Ws[c4 * 4 + 0][j] = v.x; Ws[c4 * 4 + 1][j] = v.y;
            Ws[c4 * 4 + 2][j] = v.z; Ws[c4 * 4 + 3][j] = v.w;
        }
        __syncthreads();
        #pragma unroll
        for (int n = 0; n < 64; ++n) {
            float4 hrow = *(const float4*)&HsT[n][ty * 4];
            float4 w2   = *(const float4*)&Ws[n][tx * 4];
            acc[0][0] += hrow.x * w2.x; acc[0][1] += hrow.x * w2.y; acc[0][2] += hrow.x * w2.z; acc[0][3] += hrow.x * w2.w;
            acc[1][0] += hrow.y * w2.x; acc[1][1] += hrow.y * w2.y; acc[1][2] += hrow.y * w2.z; acc[1][3] += hrow.y * w2.w;
            acc[2][0] += hrow.z * w2.x; acc[2][1] += hrow.z * w2.y; acc[2][2] += hrow.z * w2.z; acc[2][3] += hrow.z * w2.w;
            acc[3][0] += hrow.w * w2.x; acc[3][1] += hrow.w * w2.y; acc[3][2] += hrow.w * w2.z; acc[3][3] += hrow.w * w2.w;
        }
    }
    #pragma unroll
    for (int i = 0; i < 4; ++i) {
        float4 o;
        o.x = fmaxf(acc[i][0] + b2[tx * 4 + 0], 0.f);
        o.y = fmaxf(acc[i][1] + b2[tx * 4 + 1], 0.f);
        o.z = fmaxf(acc[i][2] + b2[tx * 4 + 2], 0.f);
        o.w = fmaxf(acc[i][3] + b2[tx * 4 + 3], 0.f);
        *(float4*)&Out[((size_t)(r0 + ty * 4 + i)) * 64 + tx * 4] = o;
    }
}

// ---------------------------------------------------------------------------
// Head MLP over last timestep: 64 ->256 ->64 ->32 ->1 (silu x3)
// ---------------------------------------------------------------------------
__global__ __launch_bounds__(256) void head_kernel(
    const float* __restrict__ Hf,
    const float* __restrict__ fw1, const float* __restrict__ fb1,
    const float* __restrict__ fw2, const float* __restrict__ fb2,
    const float* __restrict__ fw3, const float* __restrict__ fb3,
    const float* __restrict__ fw4, const float* __restrict__ fb4,
    float* __restrict__ out)
{
    const int b = blockIdx.x;
    const int tid = threadIdx.x;
    __shared__ float t0[64], t1[256], t2[64], t3[32];
    if (tid < 64) t0[tid] = Hf[((size_t)b * SEQL + (SEQL - 1)) * 64 + tid];
    __syncthreads();
    {
        float acc = fb1[tid];
        #pragma unroll 4
        for (int k = 0; k < 64; ++k) acc += t0[k] * fw1[tid * 64 + k];
        t1[tid] = acc / (1.f + __expf(-acc));
    }
    __syncthreads();
    if (tid < 64) {
        float acc = fb2[tid];
        #pragma unroll 4
        for (int k = 0; k < 256; ++k) acc += t1[k] * fw2[tid * 256 + k];
        t2[tid] = acc / (1.f + __expf(-acc));
    }
    __syncthreads();
    if (tid < 32) {
        float acc = fb3[tid];
        #pragma unroll 4
        for (int k = 0; k < 64; ++k) acc += t2[k] * fw3[tid * 64 + k];
        t3[tid] = acc / (1.f + __expf(-acc));
    }
    __syncthreads();
    if (tid == 0) {
        float acc = fb4[0];
        #pragma unroll
        for (int k = 0; k < 32; ++k) acc += t3[k] * fw4[k];
        out[b] = acc;
    }
}

// ---------------------------------------------------------------------------
extern "C" void kernel_launch(void* const* d_in, const int* in_sizes, int n_in,
                              void* d_out, int out_size, void* d_ws, size_t ws_size,
                              hipStream_t stream) {
    const float* x     = (const float*)d_in[0];
    const float* emb   = (const float*)d_in[1];
    const float* wih0  = (const float*)d_in[2];
    const float* whh0  = (const float*)d_in[3];
    const float* bih0  = (const float*)d_in[4];
    const float* bhh0  = (const float*)d_in[5];
    const float* wih12 = (const float*)d_in[6];
    const float* whh12 = (const float*)d_in[7];
    const float* bih12 = (const float*)d_in[8];
    const float* bhh12 = (const float*)d_in[9];
    const float* in_w1 = (const float*)d_in[10];
    const float* in_b1 = (const float*)d_in[11];
    const float* out_w1= (const float*)d_in[12];
    const float* out_b1= (const float*)d_in[13];
    const float* in_w2 = (const float*)d_in[14];
    const float* in_b2 = (const float*)d_in[15];
    const float* out_w2= (const float*)d_in[16];
    const float* out_b2= (const float*)d_in[17];
    const float* ff_w1 = (const float*)d_in[18];
    const float* ff_b1 = (const float*)d_in[19];
    const float* ff_w2 = (const float*)d_in[20];
    const float* ff_b2 = (const float*)d_in[21];
    const float* ln1_s = (const float*)d_in[22];
    const float* ln1_b = (const float*)d_in[23];
    const float* ln2_s = (const float*)d_in[24];
    const float* ln2_b = (const float*)d_in[25];
    const float* ln3_s = (const float*)d_in[26];
    const float* ln3_b = (const float*)d_in[27];
    const float* ln4_s = (const float*)d_in[28];
    const float* ln4_b = (const float*)d_in[29];
    const float* fw1   = (const float*)d_in[30];
    const float* fb1   = (const float*)d_in[31];
    const float* fw2   = (const float*)d_in[32];
    const float* fb2   = (const float*)d_in[33];
    const float* fw3   = (const float*)d_in[34];
    const float* fb3   = (const float*)d_in[35];
    const float* fw4   = (const float*)d_in[36];
    const float* fb4   = (const float*)d_in[37];

    float* ws = (float*)d_ws;
    float* X  = ws;                       // 98304*192
    float* S0 = X  + (size_t)NROWS * 192; // 98304*64
    float* S1 = S0 + (size_t)NROWS * 64;
    float* S2 = S1 + (size_t)NROWS * 64;

    // ---- GRU stack ----
    featproj_kernel<<<NROWS / 32, 192, 0, stream>>>(x, emb, wih0, bih0, X);
    gru_kernel<<<NB, 192, 0, stream>>>(X, whh0, bhh0, S0, 0);
    gemm64_kernel<<<dim3(NROWS / 128, 3), 256, 0, stream>>>(S0, wih12, bih12, X, 192);
    gru_kernel<<<NB, 192, 0, stream>>>(X, whh12, bhh12, S1, 0);
    gemm64_kernel<<<dim3(NROWS / 128, 3), 256, 0, stream>>>(S1, wih12 + 192 * 64, bih12 + 192, X, 192);
    gru_kernel<<<NB, 192, 0, stream>>>(X, whh12 + 192 * 64, bhh12 + 192, S0, 1); // g (batch-major)

    // ---- Transformer block 1 ----
    gemm64_kernel<<<dim3(NROWS / 128, 3), 256, 0, stream>>>(S0, in_w1, in_b1, X, 192);
    attn_kernel<<<dim3(2, NB), 256, 0, stream>>>(X, S1);
    gemm64_kernel<<<dim3(NROWS / 128, 1), 256, 0, stream>>>(S1, out_w1, out_b1, S2, 64);
    add_ln_kernel<<<NROWS / 4, 256, 0, stream>>>(S0, S2, ln1_s, ln1_b, S1);      // h = LN(g + a)
    ffn_kernel<<<NROWS / 64, 256, 0, stream>>>(S1, ff_w1, ff_b1, ff_w2, ff_b2, S2);
    add_ln_kernel<<<NROWS / 4, 256, 0, stream>>>(S1, S2, ln2_s, ln2_b, S0);      // h = LN(h + ffn)

    // ---- Transformer block 2 ----
    gemm64_kernel<<<dim3(NROWS / 128, 3), 256, 0, stream>>>(S0, in_w2, in_b2, X, 192);
    attn_kernel<<<dim3(2, NB), 256, 0, stream>>>(X, S1);
    gemm64_kernel<<<dim3(NROWS / 128, 1), 256, 0, stream>>>(S1, out_w2, out_b2, S2, 64);
    add_ln_kernel<<<NROWS / 4, 256, 0, stream>>>(S2, S2, ln3_s, ln3_b, S1);      // h = LN(a + a)  (per reference!)
    ffn_kernel<<<NROWS / 64, 256, 0, stream>>>(S1, ff_w1, ff_b1, ff_w2, ff_b2, S2);
    add_ln_kernel<<<NROWS / 4, 256, 0, stream>>>(S1, S2, ln4_s, ln4_b, S0);      // h = LN(h + ffn)

    // ---- Head ----
    head_kernel<<<NB, 256, 0, stream>>>(S0, fw1, fb1, fw2, fb2, fw3, fb3, fw4, fb4,
                                        (float*)d_out);
    (void)in_sizes; (void)n_in; (void)out_size; (void)ws_size;
}